// Round 4
// baseline (439.085 us; speedup 1.0000x reference)
//
#include <hip/hip_runtime.h>
#include <math.h>

#define M_ANCH   589824
#define NCLS     80
#define TOPK_N   1000
#define CAND_CAP 4096
#define NREP     16
#define NBIN     8192          /* 13-bit bins */
#define KSHIFT   19

#define SCALE_CLAMP_F 4.135166556742356f   /* log(1000/16) as f32 */
#define INV_IMG       (1.0f/2048.0f)

// ---------------- ws layout (bytes) ----------------
// [0,      524288)   hist replicas (16 x 8192 u32)  -- memset 0
// [524288, 524292)   cand count (u32)               -- memset 0
// [524292, 524296)   gbin (u32)                     -- memset 0
// [524544, 557312)   cand keys (4096 u64)
// [557312, 573312)   boxes (1000 float4)
// [573312, 577312)   labels (1000 i32)
// [577312, 581312)   valid (1000 i32)
// [581376, 709376)   sup matrix (1000*16 u64)
// [709632, 3068928)  mkeys (589824 u32)
#define WS_H1R     0
#define WS_CNT     524288
#define WS_GBIN    524292
#define WS_MEMSET  524296
#define WS_CAND    524544
#define WS_BOXES   557312
#define WS_LABELS  573312
#define WS_VALID   577312
#define WS_SUP     581376
#define WS_MKEYS   709632

// monotone float->uint map (positive floats get top bit set)
__device__ __forceinline__ unsigned fmap(unsigned b) {
    return (b & 0x80000000u) ? ~b : (b | 0x80000000u);
}
__device__ __forceinline__ unsigned funmap(unsigned k) {
    return (k & 0x80000000u) ? (k ^ 0x80000000u) : ~k;
}

// K1: per-anchor max logit -> mapped key; 13-bit LDS histogram flushed to
// 16 replicated global histograms. 1024 rows per block (16 iter x 64 rows).
__global__ __launch_bounds__(256) void k_rowmax(const float* __restrict__ cls,
                                                unsigned* __restrict__ mkeys,
                                                unsigned* __restrict__ h1r) {
    __shared__ unsigned lh[NBIN];
    int t = threadIdx.x;
    for (int b = t; b < NBIN; b += 256) lh[b] = 0;
    __syncthreads();
    int lane = t & 63, w = t >> 6;
    int part = lane & 3;                 // 4 lanes per row, 20 floats each
    int rsub = (w << 4) + (lane >> 2);   // 0..63 row-within-iteration
#pragma unroll
    for (int it = 0; it < 16; ++it) {
        int row = blockIdx.x * 1024 + it * 64 + rsub;   // covers all M_ANCH rows
        const float4* p = (const float4*)(cls + (size_t)row * NCLS) + part * 5;
        float m = -INFINITY;
#pragma unroll
        for (int i = 0; i < 5; ++i) {
            float4 v = p[i];
            m = fmaxf(m, fmaxf(fmaxf(v.x, v.y), fmaxf(v.z, v.w)));
        }
        m = fmaxf(m, __shfl_xor(m, 1));
        m = fmaxf(m, __shfl_xor(m, 2));
        if (part == 0) {
            unsigned key = fmap(__float_as_uint(m));
            mkeys[row] = key;
            atomicAdd(&lh[key >> KSHIFT], 1u);
        }
    }
    __syncthreads();
    unsigned rep = (blockIdx.x & (NREP - 1)) * NBIN;
    for (int b = t; b < NBIN; b += 256) {
        unsigned c = lh[b];
        if (c) atomicAdd(&h1r[rep + b], c);
    }
}

// K2: reduce replicas, find 13-bit bin B of the 1000th-largest key;
// gather threshold = B-1 (tie-safety margin).
__global__ __launch_bounds__(256) void k_find(const unsigned* __restrict__ h1r,
                                              unsigned* __restrict__ gbin) {
    __shared__ unsigned hist[NBIN];
    __shared__ unsigned csum[256];
    int t = threadIdx.x;
    for (int b = t; b < NBIN; b += 256) {
        unsigned s = 0;
        for (int r = 0; r < NREP; ++r) s += h1r[r * NBIN + b];
        hist[b] = s;
    }
    __syncthreads();
    unsigned cs = 0;
    for (int k = 0; k < 32; ++k) cs += hist[t * 32 + k];
    csum[t] = cs;
    __syncthreads();
    if (t == 0) {
        unsigned cum = 0, above = 0;
        int C = 0;
        for (int c = 255; c >= 0; --c) {
            if (cum + csum[c] >= TOPK_N || c == 0) { C = c; above = cum; break; }
            cum += csum[c];
        }
        int B = C * 32;
        unsigned cum2 = above;
        for (int b = C * 32 + 31; b >= C * 32; --b) {
            cum2 += hist[b];
            if (cum2 >= TOPK_N) { B = b; break; }
            if (b == C * 32) B = b;
        }
        *gbin = (B >= 1) ? (unsigned)(B - 1) : 0u;
    }
}

// K3: gather candidates above threshold as (score_bits<<32)|~idx
__global__ __launch_bounds__(256) void k_gather(const unsigned* __restrict__ mkeys,
                                                const unsigned* __restrict__ gbin,
                                                unsigned* __restrict__ cnt,
                                                unsigned long long* __restrict__ cand) {
    int i = blockIdx.x * blockDim.x + threadIdx.x;
    if (i >= M_ANCH) return;
    unsigned gb = *gbin;
    unsigned key = mkeys[i];
    if ((key >> KSHIFT) >= gb) {
        unsigned pos = atomicAdd(cnt, 1u);
        if (pos < CAND_CAP) {
            float m = __uint_as_float(funmap(key));
            // emulate np float32 sigmoid pipeline with correctly-rounded exp:
            float e = (float)exp(-(double)m);
            float sc = 1.0f / (1.0f + e);
            unsigned sb = __float_as_uint(sc);
            cand[pos] = ((unsigned long long)sb << 32) | (unsigned)(~(unsigned)i);
        }
    }
}

// K4: rank-by-count (keys are unique) + direct decode into output slot.
// rank_i = #{j : key_j > key_i} reproduces descending sort order with
// (score desc, index asc) tie-break == jax.lax.top_k.
__global__ __launch_bounds__(256) void k_rank_decode(const unsigned* __restrict__ cnt,
                                                     const unsigned long long* __restrict__ cand,
                                                     const float* __restrict__ cls,
                                                     const float* __restrict__ reg,
                                                     const float* __restrict__ anch,
                                                     float* __restrict__ out,
                                                     float4* __restrict__ boxes_ws,
                                                     int* __restrict__ lab_ws,
                                                     int* __restrict__ val_ws) {
    __shared__ unsigned long long sh[CAND_CAP];   // 32 KiB
    int t = threadIdx.x;
    unsigned n = *cnt;
    if (n > CAND_CAP) n = CAND_CAP;
    for (int k = t; k < (int)n; k += 256) sh[k] = cand[k];
    __syncthreads();
    int k = blockIdx.x * 256 + t;
    if (k >= (int)n) return;
    unsigned long long key = sh[k];
    int rank = 0;
    for (int j = 0; j < (int)n; ++j) rank += (sh[j] > key) ? 1 : 0;
    if (rank >= TOPK_N) return;
    int r = rank;
    unsigned idx = ~(unsigned)(key & 0xFFFFFFFFull);
    float sc = __uint_as_float((unsigned)(key >> 32));
    // label = argmax (first max wins, matching np.argmax)
    const float* row = cls + (size_t)idx * NCLS;
    float best = -INFINITY;
    int lbl = 0;
    for (int c = 0; c < NCLS; ++c) {
        float v = row[c];
        if (v > best) { best = v; lbl = c; }
    }
    float4 rg = ((const float4*)reg)[idx];
    float4 an = ((const float4*)anch)[idx];
    float ox = fminf(fmaxf(rg.x * an.z, -32.0f), 32.0f);
    float oy = fminf(fmaxf(rg.y * an.w, -32.0f), 32.0f);
    float cx = an.x + ox, cy = an.y + oy;
    float w = an.z * expf(fminf(rg.z, SCALE_CLAMP_F));
    float h = an.w * expf(fminf(rg.w, SCALE_CLAMP_F));
    float x1 = fminf(fmaxf((cx - 0.5f * w) * INV_IMG, 0.0f), 1.0f);
    float y1 = fminf(fmaxf((cy - 0.5f * h) * INV_IMG, 0.0f), 1.0f);
    float x2 = fminf(fmaxf((cx + 0.5f * w) * INV_IMG, 0.0f), 1.0f);
    float y2 = fminf(fmaxf((cy + 0.5f * h) * INV_IMG, 0.0f), 1.0f);
    out[r * 4 + 0] = x1;
    out[r * 4 + 1] = y1;
    out[r * 4 + 2] = x2;
    out[r * 4 + 3] = y2;
    out[4 * TOPK_N + r] = sc;
    out[5 * TOPK_N + r] = (float)lbl;
    boxes_ws[r] = make_float4(x1, y1, x2, y2);
    lab_ws[r] = lbl;
    val_ws[r] = (sc >= 0.05f) ? 1 : 0;
}

// K5: suppression bitmask matrix, row i = 16 u64 words over j
__global__ __launch_bounds__(64) void k_sup(const float4* __restrict__ boxes,
                                            const int* __restrict__ labs,
                                            unsigned long long* __restrict__ sup) {
    int i = blockIdx.x;
    int lane = threadIdx.x;
    float4 bi = boxes[i];
    float ai = (bi.z - bi.x) * (bi.w - bi.y);
    int li = labs[i];
#pragma unroll
    for (int c = 0; c < 16; ++c) {
        int j = c * 64 + lane;
        bool bit = false;
        if (j < TOPK_N) {
            float4 bj = boxes[j];
            float aj = (bj.z - bj.x) * (bj.w - bj.y);
            float xx1 = fmaxf(bi.x, bj.x), yy1 = fmaxf(bi.y, bj.y);
            float xx2 = fminf(bi.z, bj.z), yy2 = fminf(bi.w, bj.w);
            float w = fmaxf(1e-10f, xx2 - xx1);
            float h = fmaxf(1e-10f, yy2 - yy1);
            float inter = w * h;
            float iou = inter / (ai + aj - inter + 1e-10f);
            bit = (iou > 0.6f) && (labs[j] == li);
        }
        unsigned long long ball = __ballot(bit);
        if (lane == 0) sup[(size_t)i * 16 + c] = ball;
    }
}

// K6: exact greedy NMS resolve, single wave, 64-box chunks
__global__ __launch_bounds__(64) void k_nms(const unsigned long long* __restrict__ sup,
                                            const int* __restrict__ val,
                                            float* __restrict__ out_keep) {
    int lane = threadIdx.x;
    unsigned long long kw[16];
#pragma unroll
    for (int c = 0; c < 16; ++c) kw[c] = 0ull;
    unsigned long long lowmask = (lane == 0) ? 0ull : (~0ull >> (64 - lane));
    for (int c = 0; c < 16; ++c) {
        int b = c * 64 + lane;
        bool v = false;
        bool ext = false;
        unsigned long long m = 0ull;
        if (b < TOPK_N) {
            v = (val[b] != 0);
            const unsigned long long* rowp = sup + (size_t)b * 16;
            for (int w = 0; w < c; ++w) ext = ext || ((rowp[w] & kw[w]) != 0ull);
            m = rowp[c];
        }
        bool mykeep = false;
        for (int i = 0; i < 64; ++i) {
            unsigned long long ball = __ballot(mykeep);
            if (lane == i) {
                mykeep = v && !ext && ((ball & m & lowmask) == 0ull);
            }
        }
        unsigned long long ball = __ballot(mykeep);
        kw[c] = ball;
        if (b < TOPK_N) out_keep[b] = ((ball >> lane) & 1ull) ? 1.0f : 0.0f;
    }
}

extern "C" void kernel_launch(void* const* d_in, const int* in_sizes, int n_in,
                              void* d_out, int out_size, void* d_ws, size_t ws_size,
                              hipStream_t stream) {
    const float* cls  = (const float*)d_in[0];
    const float* reg  = (const float*)d_in[1];
    const float* anch = (const float*)d_in[2];
    float* out = (float*)d_out;
    char* ws = (char*)d_ws;

    unsigned* h1r  = (unsigned*)(ws + WS_H1R);
    unsigned* cnt  = (unsigned*)(ws + WS_CNT);
    unsigned* gbin = (unsigned*)(ws + WS_GBIN);
    unsigned long long* cand = (unsigned long long*)(ws + WS_CAND);
    float4* boxes = (float4*)(ws + WS_BOXES);
    int* labs     = (int*)(ws + WS_LABELS);
    int* valid    = (int*)(ws + WS_VALID);
    unsigned long long* sup = (unsigned long long*)(ws + WS_SUP);
    unsigned* mkeys = (unsigned*)(ws + WS_MKEYS);

    hipMemsetAsync(ws, 0, WS_MEMSET, stream);

    k_rowmax<<<M_ANCH / 1024, 256, 0, stream>>>(cls, mkeys, h1r);
    k_find  <<<1, 256, 0, stream>>>(h1r, gbin);
    k_gather<<<M_ANCH / 256, 256, 0, stream>>>(mkeys, gbin, cnt, cand);
    k_rank_decode<<<CAND_CAP / 256, 256, 0, stream>>>(cnt, cand, cls, reg, anch,
                                                      out, boxes, labs, valid);
    k_sup   <<<TOPK_N, 64, 0, stream>>>(boxes, labs, sup);
    k_nms   <<<1, 64, 0, stream>>>(sup, valid, out + 6 * TOPK_N);
}

// Round 5
// 385.997 us; speedup vs baseline: 1.1375x; 1.1375x over previous
//
#include <hip/hip_runtime.h>
#include <math.h>

#define M_ANCH   589824
#define NCLS     80
#define TOPK_N   1000
#define CAND_CAP 4096
#define NREP     16
#define NBIN     8192          /* 13-bit bins */
#define KSHIFT   19

#define SCALE_CLAMP_F 4.135166556742356f   /* log(1000/16) as f32 */
#define INV_IMG       (1.0f/2048.0f)

// ---------------- ws layout (bytes) ----------------
// [0,      524288)   hist replicas (16 x 8192 u32)  -- memset 0
// [524288, 524292)   cand count (u32)               -- memset 0
// [524292, 524296)   gbin (u32)                     -- memset 0
// [524544, 557312)   cand keys (4096 u64)
// [557312, 573312)   boxes (1000 float4)
// [573312, 577312)   labels (1000 i32)
// [577312, 581312)   valid (1000 i32)
// [581376, 709376)   sup matrix (1000*16 u64)
// [709632, 3068928)  mkeys (589824 u32, 16B-aligned)
#define WS_H1R     0
#define WS_CNT     524288
#define WS_GBIN    524292
#define WS_MEMSET  524296
#define WS_CAND    524544
#define WS_BOXES   557312
#define WS_LABELS  573312
#define WS_VALID   577312
#define WS_SUP     581376
#define WS_MKEYS   709632

// monotone float->uint map (positive floats get top bit set)
__device__ __forceinline__ unsigned fmap(unsigned b) {
    return (b & 0x80000000u) ? ~b : (b | 0x80000000u);
}
__device__ __forceinline__ unsigned funmap(unsigned k) {
    return (k & 0x80000000u) ? (k ^ 0x80000000u) : ~k;
}

// K1: per-anchor max logit -> mapped key; 13-bit LDS histogram flushed to
// 16 replicated global histograms. 256 rows/block, 2304 blocks (round-2
// parallelism: the 189 MB stream needs many blocks in flight).
__global__ __launch_bounds__(256) void k_rowmax(const float* __restrict__ cls,
                                                unsigned* __restrict__ mkeys,
                                                unsigned* __restrict__ h1r) {
    __shared__ unsigned lh[NBIN];
    int t = threadIdx.x;
    for (int b = t; b < NBIN; b += 256) lh[b] = 0;
    __syncthreads();
    int lane = t & 63, w = t >> 6;
    int part = lane & 3;                 // 4 lanes per row, 20 floats each
    int rsub = (w << 4) + (lane >> 2);   // 0..63 row-within-iteration
#pragma unroll
    for (int it = 0; it < 4; ++it) {
        int row = blockIdx.x * 256 + it * 64 + rsub;
        const float4* p = (const float4*)(cls + (size_t)row * NCLS) + part * 5;
        float m = -INFINITY;
#pragma unroll
        for (int i = 0; i < 5; ++i) {
            float4 v = p[i];
            m = fmaxf(m, fmaxf(fmaxf(v.x, v.y), fmaxf(v.z, v.w)));
        }
        m = fmaxf(m, __shfl_xor(m, 1));
        m = fmaxf(m, __shfl_xor(m, 2));
        if (part == 0) {
            unsigned key = fmap(__float_as_uint(m));
            mkeys[row] = key;
            atomicAdd(&lh[key >> KSHIFT], 1u);
        }
    }
    __syncthreads();
    unsigned rep = (blockIdx.x & (NREP - 1)) * NBIN;
    for (int b = t; b < NBIN; b += 256) {
        unsigned c = lh[b];
        if (c) atomicAdd(&h1r[rep + b], c);
    }
}

// K2: reduce replicas (1024 threads), find 13-bit bin B of the 1000th-largest
// key; gather threshold = B-1 (tie-safety margin: 0.25 logit >> any score-tie
// logit window ~3e-5).
__global__ __launch_bounds__(1024) void k_find(const unsigned* __restrict__ h1r,
                                               unsigned* __restrict__ gbin) {
    __shared__ unsigned hist[NBIN];
    __shared__ unsigned csum[256];
    int t = threadIdx.x;
    for (int b = t; b < NBIN; b += 1024) {
        unsigned s = 0;
#pragma unroll
        for (int r = 0; r < NREP; ++r) s += h1r[r * NBIN + b];
        hist[b] = s;
    }
    __syncthreads();
    if (t < 256) {
        unsigned cs = 0;
        for (int k = 0; k < 32; ++k) cs += hist[t * 32 + k];
        csum[t] = cs;
    }
    __syncthreads();
    if (t == 0) {
        unsigned cum = 0, above = 0;
        int C = 0;
        for (int c = 255; c >= 0; --c) {
            if (cum + csum[c] >= TOPK_N || c == 0) { C = c; above = cum; break; }
            cum += csum[c];
        }
        int B = C * 32;
        unsigned cum2 = above;
        for (int b = C * 32 + 31; b >= C * 32; --b) {
            cum2 += hist[b];
            if (cum2 >= TOPK_N) { B = b; break; }
            if (b == C * 32) B = b;
        }
        *gbin = (B >= 1) ? (unsigned)(B - 1) : 0u;
    }
}

// K3: gather candidates above threshold as (score_bits<<32)|~idx.
// 8 keys/thread: fewer candidate-bearing waves -> fewer serialized
// same-address wave-atomics on the single counter.
__global__ __launch_bounds__(256) void k_gather(const uint4* __restrict__ mk4,
                                                const unsigned* __restrict__ gbin,
                                                unsigned* __restrict__ cnt,
                                                unsigned long long* __restrict__ cand) {
    int tid = blockIdx.x * 256 + threadIdx.x;
    unsigned gb = *gbin;
    uint4 a = mk4[tid * 2];
    uint4 b4 = mk4[tid * 2 + 1];
    unsigned keys[8] = {a.x, a.y, a.z, a.w, b4.x, b4.y, b4.z, b4.w};
    int lc = 0;
    unsigned sel[8];
#pragma unroll
    for (int q = 0; q < 8; ++q)
        if ((keys[q] >> KSHIFT) >= gb) sel[lc++] = (unsigned)q;
    if (lc) {
        unsigned base = atomicAdd(cnt, (unsigned)lc);
        for (int q = 0; q < lc; ++q) {
            unsigned pos = base + (unsigned)q;
            if (pos < CAND_CAP) {
                unsigned i = (unsigned)tid * 8u + sel[q];
                float m = __uint_as_float(funmap(keys[sel[q]]));
                // emulate np float32 sigmoid pipeline (correctly-rounded exp):
                float e = (float)exp(-(double)m);
                float sc = 1.0f / (1.0f + e);
                cand[pos] = ((unsigned long long)__float_as_uint(sc) << 32)
                            | (unsigned)(~i);
            }
        }
    }
}

// K4: rank-by-count (keys unique) + direct decode into output slot.
// rank_i = #{j : key_j > key_i} == descending sort order with
// (score desc, index asc) tie-break == jax.lax.top_k.
__global__ __launch_bounds__(256) void k_rank_decode(const unsigned* __restrict__ cnt,
                                                     const unsigned long long* __restrict__ cand,
                                                     const float* __restrict__ cls,
                                                     const float* __restrict__ reg,
                                                     const float* __restrict__ anch,
                                                     float* __restrict__ out,
                                                     float4* __restrict__ boxes_ws,
                                                     int* __restrict__ lab_ws,
                                                     int* __restrict__ val_ws) {
    __shared__ unsigned long long sh[CAND_CAP];   // 32 KiB
    int t = threadIdx.x;
    unsigned n = *cnt;
    if (n > CAND_CAP) n = CAND_CAP;
    for (int k = t; k < (int)n; k += 256) sh[k] = cand[k];
    __syncthreads();
    int k = blockIdx.x * 256 + t;
    if (k >= (int)n) return;
    unsigned long long key = sh[k];
    int rank = 0;
    for (int j = 0; j < (int)n; ++j) rank += (sh[j] > key) ? 1 : 0;
    if (rank >= TOPK_N) return;
    int r = rank;
    unsigned idx = ~(unsigned)(key & 0xFFFFFFFFull);
    float sc = __uint_as_float((unsigned)(key >> 32));
    // label = argmax (first max wins, matching np.argmax)
    const float* row = cls + (size_t)idx * NCLS;
    float best = -INFINITY;
    int lbl = 0;
    for (int c = 0; c < NCLS; ++c) {
        float v = row[c];
        if (v > best) { best = v; lbl = c; }
    }
    float4 rg = ((const float4*)reg)[idx];
    float4 an = ((const float4*)anch)[idx];
    float ox = fminf(fmaxf(rg.x * an.z, -32.0f), 32.0f);
    float oy = fminf(fmaxf(rg.y * an.w, -32.0f), 32.0f);
    float cx = an.x + ox, cy = an.y + oy;
    float w = an.z * expf(fminf(rg.z, SCALE_CLAMP_F));
    float h = an.w * expf(fminf(rg.w, SCALE_CLAMP_F));
    float x1 = fminf(fmaxf((cx - 0.5f * w) * INV_IMG, 0.0f), 1.0f);
    float y1 = fminf(fmaxf((cy - 0.5f * h) * INV_IMG, 0.0f), 1.0f);
    float x2 = fminf(fmaxf((cx + 0.5f * w) * INV_IMG, 0.0f), 1.0f);
    float y2 = fminf(fmaxf((cy + 0.5f * h) * INV_IMG, 0.0f), 1.0f);
    out[r * 4 + 0] = x1;
    out[r * 4 + 1] = y1;
    out[r * 4 + 2] = x2;
    out[r * 4 + 3] = y2;
    out[4 * TOPK_N + r] = sc;
    out[5 * TOPK_N + r] = (float)lbl;
    boxes_ws[r] = make_float4(x1, y1, x2, y2);
    lab_ws[r] = lbl;
    val_ws[r] = (sc >= 0.05f) ? 1 : 0;
}

// K5: suppression bitmask matrix — LOWER TRIANGLE only (words c <= i>>6);
// NMS never reads the upper words.
__global__ __launch_bounds__(64) void k_sup(const float4* __restrict__ boxes,
                                            const int* __restrict__ labs,
                                            unsigned long long* __restrict__ sup) {
    int i = blockIdx.x;
    int lane = threadIdx.x;
    int cmax = i >> 6;
    float4 bi = boxes[i];
    float ai = (bi.z - bi.x) * (bi.w - bi.y);
    int li = labs[i];
    for (int c = 0; c <= cmax; ++c) {
        int j = c * 64 + lane;
        bool bit = false;
        if (j < TOPK_N) {
            float4 bj = boxes[j];
            float aj = (bj.z - bj.x) * (bj.w - bj.y);
            float xx1 = fmaxf(bi.x, bj.x), yy1 = fmaxf(bi.y, bj.y);
            float xx2 = fminf(bi.z, bj.z), yy2 = fminf(bi.w, bj.w);
            float w = fmaxf(1e-10f, xx2 - xx1);
            float h = fmaxf(1e-10f, yy2 - yy1);
            float inter = w * h;
            float iou = inter / (ai + aj - inter + 1e-10f);
            bit = (iou > 0.6f) && (labs[j] == li);
        }
        unsigned long long ball = __ballot(bit);
        if (lane == 0) sup[(size_t)i * 16 + c] = ball;
    }
}

// K6: exact greedy NMS, single wave, 64-box chunks. Fast path: when a chunk
// has no intra-chunk suppression edges (common: ~100 suppress bits in 1M
// pairs), resolve all 64 lanes at once; else 64-step serial resolve.
__global__ __launch_bounds__(64) void k_nms(const unsigned long long* __restrict__ sup,
                                            const int* __restrict__ val,
                                            float* __restrict__ out_keep) {
    int lane = threadIdx.x;
    unsigned long long kw[16];
#pragma unroll
    for (int c = 0; c < 16; ++c) kw[c] = 0ull;
    unsigned long long lowmask = (lane == 0) ? 0ull : (~0ull >> (64 - lane));
    for (int c = 0; c < 16; ++c) {
        int b = c * 64 + lane;
        bool v = false;
        bool ext = false;
        unsigned long long m = 0ull;
        if (b < TOPK_N) {
            v = (val[b] != 0);
            const unsigned long long* rowp = sup + (size_t)b * 16;
            for (int w = 0; w < c; ++w) ext = ext || ((rowp[w] & kw[w]) != 0ull);
            m = rowp[c];
        }
        unsigned long long inchunk = m & lowmask;
        bool mykeep;
        if (__ballot(inchunk != 0ull) == 0ull) {
            mykeep = v && !ext;                     // no intra-chunk deps
        } else {
            mykeep = false;
            for (int i = 0; i < 64; ++i) {
                unsigned long long ball = __ballot(mykeep);
                if (lane == i) mykeep = v && !ext && ((ball & inchunk) == 0ull);
            }
        }
        unsigned long long ball2 = __ballot(mykeep);
        kw[c] = ball2;
        if (b < TOPK_N) out_keep[b] = ((ball2 >> lane) & 1ull) ? 1.0f : 0.0f;
    }
}

extern "C" void kernel_launch(void* const* d_in, const int* in_sizes, int n_in,
                              void* d_out, int out_size, void* d_ws, size_t ws_size,
                              hipStream_t stream) {
    const float* cls  = (const float*)d_in[0];
    const float* reg  = (const float*)d_in[1];
    const float* anch = (const float*)d_in[2];
    float* out = (float*)d_out;
    char* ws = (char*)d_ws;

    unsigned* h1r  = (unsigned*)(ws + WS_H1R);
    unsigned* cnt  = (unsigned*)(ws + WS_CNT);
    unsigned* gbin = (unsigned*)(ws + WS_GBIN);
    unsigned long long* cand = (unsigned long long*)(ws + WS_CAND);
    float4* boxes = (float4*)(ws + WS_BOXES);
    int* labs     = (int*)(ws + WS_LABELS);
    int* valid    = (int*)(ws + WS_VALID);
    unsigned long long* sup = (unsigned long long*)(ws + WS_SUP);
    unsigned* mkeys = (unsigned*)(ws + WS_MKEYS);

    hipMemsetAsync(ws, 0, WS_MEMSET, stream);

    k_rowmax<<<M_ANCH / 256, 256, 0, stream>>>(cls, mkeys, h1r);
    k_find  <<<1, 1024, 0, stream>>>(h1r, gbin);
    k_gather<<<M_ANCH / (256 * 8), 256, 0, stream>>>((const uint4*)mkeys, gbin, cnt, cand);
    k_rank_decode<<<CAND_CAP / 256, 256, 0, stream>>>(cnt, cand, cls, reg, anch,
                                                      out, boxes, labs, valid);
    k_sup   <<<TOPK_N, 64, 0, stream>>>(boxes, labs, sup);
    k_nms   <<<1, 64, 0, stream>>>(sup, valid, out + 6 * TOPK_N);
}